// Round 1
// baseline (98.960 us; speedup 1.0000x reference)
//
#include <hip/hip_runtime.h>
#include <hip/hip_bf16.h>

// out[i, :] = emb[ids[i], :]  — the reference's sort/gather/inverse-sort is the identity.
// ids: [D*N] = 524288 int32, emb: [1M, 128] f32, out: [D*N, 128] f32.
// 32 lanes per row, one float4 (16B) per lane: coalesced 512B row copies.

#define EMB 128
#define LANES_PER_ROW 32  // EMB/4 floats per float4

__global__ void __launch_bounds__(256)
TFDistributedEmbedding_76828374991710_kernel(const int* __restrict__ ids,
                                             const float* __restrict__ emb,
                                             float* __restrict__ out,
                                             int n_ids) {
    long long gtid = (long long)blockIdx.x * blockDim.x + threadIdx.x;
    int row  = (int)(gtid >> 5);       // gtid / LANES_PER_ROW
    int lane = (int)(gtid & 31);       // gtid % LANES_PER_ROW
    if (row >= n_ids) return;

    int id = ids[row];
    const float4* __restrict__ src = reinterpret_cast<const float4*>(emb + (long long)id * EMB);
    float4* __restrict__ dst       = reinterpret_cast<float4*>(out + (long long)row * EMB);
    dst[lane] = src[lane];
}

extern "C" void kernel_launch(void* const* d_in, const int* in_sizes, int n_in,
                              void* d_out, int out_size, void* d_ws, size_t ws_size,
                              hipStream_t stream) {
    const int*   ids = (const int*)d_in[0];     // [8, 65536] int32
    const float* emb = (const float*)d_in[1];   // [1M, 128] f32
    float*       out = (float*)d_out;           // [8, 65536, 128] f32

    int n_ids = in_sizes[0];                    // 524288
    long long total_threads = (long long)n_ids * LANES_PER_ROW;
    int block = 256;
    int grid = (int)((total_threads + block - 1) / block);

    TFDistributedEmbedding_76828374991710_kernel<<<grid, block, 0, stream>>>(ids, emb, out, n_ids);
}